// Round 2
// baseline (424.259 us; speedup 1.0000x reference)
//
#include <hip/hip_runtime.h>

#define Bdim 512
#define Tdim 2000
#define Ddim 20
#define Hdim 128
#define Cdim 10
#define TB 128          // timesteps per LDS tile
#define BETA 0.95f
#define THR 0.8f

__global__ __launch_bounds__(Hdim, 1) void snn_fused_kernel(
    const float* __restrict__ x,   // [B,T,D]
    const float* __restrict__ W1,  // [H,D]
    const float* __restrict__ b1,  // [H]
    const float* __restrict__ W2,  // [C,H]
    const float* __restrict__ b2,  // [C]
    float* __restrict__ out)       // [B,C]
{
    const int b = blockIdx.x;
    const int h = threadIdx.x;

    __shared__ float xs[2][TB * Ddim];   // 2 * 10240 B
    __shared__ float cnt_s[Hdim];

    // W1 row + bias in registers
    float w[Ddim];
#pragma unroll
    for (int d = 0; d < Ddim; ++d) w[d] = W1[h * Ddim + d];
    const float bias = b1[h];

    const float* xb = x + (size_t)b * Tdim * Ddim;

    // stage tile 0
    {
        const int n4 = TB * Ddim / 4;   // 640
        const float4* src = reinterpret_cast<const float4*>(xb);
        float4* dst = reinterpret_cast<float4*>(xs[0]);
#pragma unroll
        for (int k = 0; k < 5; ++k)
            if (h + 128 * k < n4) dst[h + 128 * k] = src[h + 128 * k];
    }
    __syncthreads();

    float mem = 0.0f;
    float cnt = 0.0f;
    int cur = 0;
    const int NT = (Tdim + TB - 1) / TB;   // 16 (last tile nt=80; both 128 and 80 are %4==0)

    for (int tile = 0; tile < NT; ++tile) {
        const int t0 = tile * TB;
        const int nt = min(TB, Tdim - t0);

        // prefetch next tile into registers (guards match stores below)
        float4 r0, r1, r2, r3, r4;
        int n4n = 0;
        if (tile + 1 < NT) {
            const int t1 = (tile + 1) * TB;
            n4n = (min(TB, Tdim - t1) * Ddim) / 4;
            const float4* src = reinterpret_cast<const float4*>(xb + (size_t)t1 * Ddim);
            if (h         < n4n) r0 = src[h];
            if (h + 128   < n4n) r1 = src[h + 128];
            if (h + 256   < n4n) r2 = src[h + 256];
            if (h + 384   < n4n) r3 = src[h + 384];
            if (h + 512   < n4n) r4 = src[h + 512];
        }

        const float* xt = xs[cur];

        // depth-4 register ring over timesteps: slot = t & 3.
        // Preload t = 0,1,2; each STEP(K) prefetches t = tl+K+3 into slot
        // (K+3)&3 while computing t = tl+K from slot K. Prefetch distance =
        // 3 steps (~120 cyc of FMA issue) ~= LDS read latency.
        float4 pre[4][5];
#pragma unroll
        for (int s = 0; s < 3; ++s) {
            const float4* q = reinterpret_cast<const float4*>(xt + s * Ddim);
            pre[s][0] = q[0]; pre[s][1] = q[1]; pre[s][2] = q[2]; pre[s][3] = q[3]; pre[s][4] = q[4];
        }

#define SNN_STEP(K) {                                                                              \
            const int tp = tl + (K) + 3;                                                           \
            if (tp < nt) {                                                                         \
                const float4* q = reinterpret_cast<const float4*>(xt + tp * Ddim);                 \
                pre[((K)+3)&3][0] = q[0]; pre[((K)+3)&3][1] = q[1];                                \
                pre[((K)+3)&3][2] = q[2]; pre[((K)+3)&3][3] = q[3]; pre[((K)+3)&3][4] = q[4];      \
            }                                                                                      \
            const float4 a0 = pre[K][0], a1 = pre[K][1], a2 = pre[K][2],                           \
                         a3 = pre[K][3], a4 = pre[K][4];                                           \
            float s0 = fmaf(a0.x, w[0], fmaf(a1.x, w[4], fmaf(a2.x, w[8],  fmaf(a3.x, w[12], a4.x * w[16])))); \
            float s1 = fmaf(a0.y, w[1], fmaf(a1.y, w[5], fmaf(a2.y, w[9],  fmaf(a3.y, w[13], a4.y * w[17])))); \
            float s2 = fmaf(a0.z, w[2], fmaf(a1.z, w[6], fmaf(a2.z, w[10], fmaf(a3.z, w[14], a4.z * w[18])))); \
            float s3 = fmaf(a0.w, w[3], fmaf(a1.w, w[7], fmaf(a2.w, w[11], fmaf(a3.w, w[15], a4.w * w[19])))); \
            const float curr = ((s0 + s1) + (s2 + s3)) + bias;                                     \
            const float reset = (mem > THR) ? THR : 0.0f;                                          \
            mem = fmaf(BETA, mem, curr) - reset;                                                   \
            cnt += (mem > THR) ? 1.0f : 0.0f;                                                      \
        }

        for (int tl = 0; tl < nt; tl += 4) {
            SNN_STEP(0)
            SNN_STEP(1)
            SNN_STEP(2)
            SNN_STEP(3)
        }
#undef SNN_STEP

        // store prefetched tile into the other buffer, then sync
        if (tile + 1 < NT) {
            float4* dst = reinterpret_cast<float4*>(xs[cur ^ 1]);
            if (h         < n4n) dst[h]         = r0;
            if (h + 128   < n4n) dst[h + 128]   = r1;
            if (h + 256   < n4n) dst[h + 256]   = r2;
            if (h + 384   < n4n) dst[h + 384]   = r3;
            if (h + 512   < n4n) dst[h + 512]   = r4;
            __syncthreads();
            cur ^= 1;
        }
    }

    // fused epilogue: logits[b,:] from spike counts of this block
    cnt_s[h] = cnt;
    __syncthreads();
    if (h < Cdim) {
        float dot = 0.0f;
#pragma unroll
        for (int k = 0; k < Hdim; ++k)
            dot = fmaf(cnt_s[k], W2[h * Hdim + k], dot);
        const float Tf = (float)Tdim;
        const float scale = 1.0f / Tf + 0.1f / (Tf + 1e-6f);
        out[b * Cdim + h] = fmaf(dot, scale, 1.1f * b2[h]);
    }
}

extern "C" void kernel_launch(void* const* d_in, const int* in_sizes, int n_in,
                              void* d_out, int out_size, void* d_ws, size_t ws_size,
                              hipStream_t stream) {
    const float* x  = (const float*)d_in[0];
    const float* W1 = (const float*)d_in[1];
    const float* b1 = (const float*)d_in[2];
    const float* W2 = (const float*)d_in[3];
    const float* b2 = (const float*)d_in[4];
    float* out = (float*)d_out;

    snn_fused_kernel<<<dim3(Bdim), dim3(Hdim), 0, stream>>>(x, W1, b1, W2, b2, out);
}

// Round 3
// 266.142 us; speedup vs baseline: 1.5941x; 1.5941x over previous
//
#include <hip/hip_runtime.h>

#define Bdim 512
#define Tdim 2000
#define Ddim 20
#define Hdim 128
#define Cdim 10
#define TB 128          // timesteps per LDS tile
#define TBP (TB + 4)    // padded rows so unconditional prefetch stays in-bounds
#define BETA 0.95f
#define THR 0.8f

__global__ __launch_bounds__(Hdim, 1) void snn_fused_kernel(
    const float* __restrict__ x,   // [B,T,D]
    const float* __restrict__ W1,  // [H,D]
    const float* __restrict__ b1,  // [H]
    const float* __restrict__ W2,  // [C,H]
    const float* __restrict__ b2,  // [C]
    float* __restrict__ out)       // [B,C]
{
    const int b = blockIdx.x;
    const int h = threadIdx.x;

    __shared__ float xs[2][TBP * Ddim];   // 2 * 10560 B
    __shared__ float cnt_s[Hdim];

    // W1 row + bias in registers
    float w[Ddim];
#pragma unroll
    for (int d = 0; d < Ddim; ++d) w[d] = W1[h * Ddim + d];
    const float bias = b1[h];

    const float* xb = x + (size_t)b * Tdim * Ddim;

    // stage tile 0
    {
        const int n4 = TB * Ddim / 4;   // 640
        const float4* src = reinterpret_cast<const float4*>(xb);
        float4* dst = reinterpret_cast<float4*>(xs[0]);
#pragma unroll
        for (int k = 0; k < 5; ++k)
            if (h + 128 * k < n4) dst[h + 128 * k] = src[h + 128 * k];
    }
    __syncthreads();

    float mem = 0.0f;
    float cnt = 0.0f;
    float reset = 0.0f;              // carried: THR if spike at previous step
    int cur = 0;
    const int NT = (Tdim + TB - 1) / TB;   // 16 (last tile nt=80; both 128 and 80 are %4==0)

    for (int tile = 0; tile < NT; ++tile) {
        const int t0 = tile * TB;
        const int nt = min(TB, Tdim - t0);

        // prefetch next tile from global into registers
        float4 r0, r1, r2, r3, r4;
        int n4n = 0;
        if (tile + 1 < NT) {
            const int t1 = (tile + 1) * TB;
            n4n = (min(TB, Tdim - t1) * Ddim) / 4;
            const float4* src = reinterpret_cast<const float4*>(xb + (size_t)t1 * Ddim);
            if (h         < n4n) r0 = src[h];
            if (h + 128   < n4n) r1 = src[h + 128];
            if (h + 256   < n4n) r2 = src[h + 256];
            if (h + 384   < n4n) r3 = src[h + 384];
            if (h + 512   < n4n) r4 = src[h + 512];
        }

        const float* xt = xs[cur];

        // Depth-4 register ring over timesteps, UNCONDITIONAL prefetch
        // (rows up to nt+2 < TBP are always in-bounds; garbage rows are
        // prefetched but never computed since the loop covers t < nt and
        // nt % 4 == 0). No per-step guards -> no phi-merge mov bloat.
        float4 pre[4][5];
#pragma unroll
        for (int s = 0; s < 3; ++s) {
            const float4* q = reinterpret_cast<const float4*>(xt + s * Ddim);
            pre[s][0] = q[0]; pre[s][1] = q[1]; pre[s][2] = q[2]; pre[s][3] = q[3]; pre[s][4] = q[4];
        }

#define SNN_STEP(K) {                                                                              \
            const float4* q = reinterpret_cast<const float4*>(xt + (tl + (K) + 3) * Ddim);         \
            pre[((K)+3)&3][0] = q[0]; pre[((K)+3)&3][1] = q[1];                                    \
            pre[((K)+3)&3][2] = q[2]; pre[((K)+3)&3][3] = q[3]; pre[((K)+3)&3][4] = q[4];          \
            const float4 a0 = pre[K][0], a1 = pre[K][1], a2 = pre[K][2],                           \
                         a3 = pre[K][3], a4 = pre[K][4];                                           \
            float s0 = fmaf(a0.x, w[0], fmaf(a1.x, w[4], fmaf(a2.x, w[8],  fmaf(a3.x, w[12], fmaf(a4.x, w[16], bias))))); \
            float s1 = fmaf(a0.y, w[1], fmaf(a1.y, w[5], fmaf(a2.y, w[9],  fmaf(a3.y, w[13], a4.y * w[17])))); \
            float s2 = fmaf(a0.z, w[2], fmaf(a1.z, w[6], fmaf(a2.z, w[10], fmaf(a3.z, w[14], a4.z * w[18])))); \
            float s3 = fmaf(a0.w, w[3], fmaf(a1.w, w[7], fmaf(a2.w, w[11], fmaf(a3.w, w[15], a4.w * w[19])))); \
            const float curr = ((s0 + s1) + (s2 + s3));                                            \
            mem = fmaf(BETA, mem, curr) - reset;                                                   \
            const bool sp = mem > THR;                                                             \
            cnt += sp ? 1.0f : 0.0f;                                                               \
            reset = sp ? THR : 0.0f;                                                               \
        }

        for (int tl = 0; tl < nt; tl += 4) {
            SNN_STEP(0)
            SNN_STEP(1)
            SNN_STEP(2)
            SNN_STEP(3)
        }
#undef SNN_STEP

        // store prefetched tile into the other buffer, then sync
        if (tile + 1 < NT) {
            float4* dst = reinterpret_cast<float4*>(xs[cur ^ 1]);
            if (h         < n4n) dst[h]         = r0;
            if (h + 128   < n4n) dst[h + 128]   = r1;
            if (h + 256   < n4n) dst[h + 256]   = r2;
            if (h + 384   < n4n) dst[h + 384]   = r3;
            if (h + 512   < n4n) dst[h + 512]   = r4;
            __syncthreads();
            cur ^= 1;
        }
    }

    // fused epilogue: logits[b,:] from spike counts of this block
    cnt_s[h] = cnt;
    __syncthreads();
    if (h < Cdim) {
        float dot = 0.0f;
#pragma unroll
        for (int k = 0; k < Hdim; ++k)
            dot = fmaf(cnt_s[k], W2[h * Hdim + k], dot);
        const float Tf = (float)Tdim;
        const float scale = 1.0f / Tf + 0.1f / (Tf + 1e-6f);
        out[b * Cdim + h] = fmaf(dot, scale, 1.1f * b2[h]);
    }
}

extern "C" void kernel_launch(void* const* d_in, const int* in_sizes, int n_in,
                              void* d_out, int out_size, void* d_ws, size_t ws_size,
                              hipStream_t stream) {
    const float* x  = (const float*)d_in[0];
    const float* W1 = (const float*)d_in[1];
    const float* b1 = (const float*)d_in[2];
    const float* W2 = (const float*)d_in[3];
    const float* b2 = (const float*)d_in[4];
    float* out = (float*)d_out;

    snn_fused_kernel<<<dim3(Bdim), dim3(Hdim), 0, stream>>>(x, W1, b1, W2, b2, out);
}

// Round 4
// 257.887 us; speedup vs baseline: 1.6451x; 1.0320x over previous
//
#include <hip/hip_runtime.h>

#define Bdim 512
#define Tdim 2000
#define Ddim 20
#define Hdim 128
#define Cdim 10
#define TB 128          // timesteps per LDS tile
#define TBP (TB + 4)    // padded rows: unconditional 3-ahead prefetch stays in-bounds
#define BETA 0.95f
#define THR 0.8f

typedef float f32x4 __attribute__((ext_vector_type(4)));

__global__ __launch_bounds__(Hdim, 1) void snn_fused_kernel(
    const float* __restrict__ x,   // [B,T,D]
    const float* __restrict__ W1,  // [H,D]
    const float* __restrict__ b1,  // [H]
    const float* __restrict__ W2,  // [C,H]
    const float* __restrict__ b2,  // [C]
    float* __restrict__ out)       // [B,C]
{
    const int b = blockIdx.x;
    const int h = threadIdx.x;

    __shared__ float xs[2][TBP * Ddim];   // 2 * 10560 B
    __shared__ float cnt_s[Hdim];

    float w[Ddim];
#pragma unroll
    for (int d = 0; d < Ddim; ++d) w[d] = W1[h * Ddim + d];
    const float bias = b1[h];

    const float* xb = x + (size_t)b * Tdim * Ddim;

    // stage tile 0
    {
        const int n4 = TB * Ddim / 4;   // 640
        const float4* src = reinterpret_cast<const float4*>(xb);
        float4* dst = reinterpret_cast<float4*>(xs[0]);
#pragma unroll
        for (int k = 0; k < 5; ++k)
            if (h + 128 * k < n4) dst[h + 128 * k] = src[h + 128 * k];
    }
    __syncthreads();

    float mem = 0.0f;
    float cnt = 0.0f;
    float reset = 0.0f;              // THR if spike at previous step, else 0
    int cur = 0;
    const int NT = (Tdim + TB - 1) / TB;   // 16 tiles (15 x 128 + 1 x 80; both % 8 == 0)

    // Depth-3 lookahead ring, 4 slots x 5 float4, pinned in VGPRs by asm outputs.
    f32x4 ring[4][5];

    for (int tile = 0; tile < NT; ++tile) {
        const int t0 = tile * TB;
        const int nt = min(TB, Tdim - t0);

        // global -> register prefetch of next tile (vmcnt; overlaps with compute)
        float4 r0, r1, r2, r3, r4;
        int n4n = 0;
        if (tile + 1 < NT) {
            const int t1 = (tile + 1) * TB;
            n4n = (min(TB, Tdim - t1) * Ddim) / 4;
            const float4* src = reinterpret_cast<const float4*>(xb + (size_t)t1 * Ddim);
            if (h         < n4n) r0 = src[h];
            if (h + 128   < n4n) r1 = src[h + 128];
            if (h + 256   < n4n) r2 = src[h + 256];
            if (h + 384   < n4n) r3 = src[h + 384];
            if (h + 512   < n4n) r4 = src[h + 512];
        }

        const float* xt = xs[cur];
        // Low 32 bits of a generic LDS pointer = byte offset within LDS.
        const uint32_t abase = (uint32_t)(uintptr_t)xt;

        // ---- prologue: issue rows 0,1,2 (15 ds_reads outstanding, no wait) ----
#define SNN_PRE_ROW(S)                                                                                      \
        asm volatile("ds_read_b128 %0, %1 offset:%c2" : "=v"(ring[S][0]) : "v"(abase), "n"((S)*80 +  0));   \
        asm volatile("ds_read_b128 %0, %1 offset:%c2" : "=v"(ring[S][1]) : "v"(abase), "n"((S)*80 + 16));   \
        asm volatile("ds_read_b128 %0, %1 offset:%c2" : "=v"(ring[S][2]) : "v"(abase), "n"((S)*80 + 32));   \
        asm volatile("ds_read_b128 %0, %1 offset:%c2" : "=v"(ring[S][3]) : "v"(abase), "n"((S)*80 + 48));   \
        asm volatile("ds_read_b128 %0, %1 offset:%c2" : "=v"(ring[S][4]) : "v"(abase), "n"((S)*80 + 64));
        SNN_PRE_ROW(0)
        SNN_PRE_ROW(1)
        SNN_PRE_ROW(2)
#undef SNN_PRE_ROW

        // ---- steady state: per step, issue t+3, wait t, compute t ----
        // After issuing t+3: outstanding = {t+1,t+2,t+3} x 5 = 15 (+ t's if slow).
        // lgkmcnt(15) => t's 5 reads complete (DS retires in order).
#define SNN_STEP(K)                                                                                                        \
        asm volatile("ds_read_b128 %0, %1 offset:%c2" : "=v"(ring[((K)+3)&3][0]) : "v"(gaddr), "n"((((K)+3)*80) +  0));    \
        asm volatile("ds_read_b128 %0, %1 offset:%c2" : "=v"(ring[((K)+3)&3][1]) : "v"(gaddr), "n"((((K)+3)*80) + 16));    \
        asm volatile("ds_read_b128 %0, %1 offset:%c2" : "=v"(ring[((K)+3)&3][2]) : "v"(gaddr), "n"((((K)+3)*80) + 32));    \
        asm volatile("ds_read_b128 %0, %1 offset:%c2" : "=v"(ring[((K)+3)&3][3]) : "v"(gaddr), "n"((((K)+3)*80) + 48));    \
        asm volatile("ds_read_b128 %0, %1 offset:%c2" : "=v"(ring[((K)+3)&3][4]) : "v"(gaddr), "n"((((K)+3)*80) + 64));    \
        asm volatile("s_waitcnt lgkmcnt(15)" ::: "memory");                                                                \
        __builtin_amdgcn_sched_barrier(0);                                                                                 \
        {                                                                                                                  \
            const f32x4 a0 = ring[(K)&3][0], a1 = ring[(K)&3][1], a2 = ring[(K)&3][2],                                     \
                        a3 = ring[(K)&3][3], a4 = ring[(K)&3][4];                                                          \
            float s0 = fmaf(a0.x, w[0], fmaf(a1.x, w[4], fmaf(a2.x, w[8],  fmaf(a3.x, w[12], fmaf(a4.x, w[16], bias)))));  \
            float s1 = fmaf(a0.y, w[1], fmaf(a1.y, w[5], fmaf(a2.y, w[9],  fmaf(a3.y, w[13], fmaf(a4.y, w[17], -reset)))));\
            float s2 = fmaf(a0.z, w[2], fmaf(a1.z, w[6], fmaf(a2.z, w[10], fmaf(a3.z, w[14], a4.z * w[18]))));             \
            float s3 = fmaf(a0.w, w[3], fmaf(a1.w, w[7], fmaf(a2.w, w[11], fmaf(a3.w, w[15], a4.w * w[19]))));             \
            mem = fmaf(BETA, mem, ((s0 + s1) + (s2 + s3)));                                                                \
            const bool sp = mem > THR;                                                                                     \
            cnt += sp ? 1.0f : 0.0f;                                                                                       \
            reset = sp ? THR : 0.0f;                                                                                       \
        }

        for (int tl = 0; tl < nt; tl += 8) {
            const uint32_t gaddr = abase + (uint32_t)tl * 80u;
            SNN_STEP(0)
            SNN_STEP(1)
            SNN_STEP(2)
            SNN_STEP(3)
            SNN_STEP(4)
            SNN_STEP(5)
            SNN_STEP(6)
            SNN_STEP(7)
        }
#undef SNN_STEP
        // 15 phantom reads (rows nt..nt+2, within TBP pad) remain outstanding;
        // __syncthreads below drains lgkmcnt.

        // store prefetched tile into the other buffer, then sync
        if (tile + 1 < NT) {
            float4* dst = reinterpret_cast<float4*>(xs[cur ^ 1]);
            if (h         < n4n) dst[h]         = r0;
            if (h + 128   < n4n) dst[h + 128]   = r1;
            if (h + 256   < n4n) dst[h + 256]   = r2;
            if (h + 384   < n4n) dst[h + 384]   = r3;
            if (h + 512   < n4n) dst[h + 512]   = r4;
        }
        __syncthreads();
        cur ^= 1;
    }

    // fused epilogue: logits[b,:] from spike counts of this block
    cnt_s[h] = cnt;
    __syncthreads();
    if (h < Cdim) {
        float dot = 0.0f;
#pragma unroll
        for (int k = 0; k < Hdim; ++k)
            dot = fmaf(cnt_s[k], W2[h * Hdim + k], dot);
        const float Tf = (float)Tdim;
        const float scale = 1.0f / Tf + 0.1f / (Tf + 1e-6f);
        out[b * Cdim + h] = fmaf(dot, scale, 1.1f * b2[h]);
    }
}

extern "C" void kernel_launch(void* const* d_in, const int* in_sizes, int n_in,
                              void* d_out, int out_size, void* d_ws, size_t ws_size,
                              hipStream_t stream) {
    const float* x  = (const float*)d_in[0];
    const float* W1 = (const float*)d_in[1];
    const float* b1 = (const float*)d_in[2];
    const float* W2 = (const float*)d_in[3];
    const float* b2 = (const float*)d_in[4];
    float* out = (float*)d_out;

    snn_fused_kernel<<<dim3(Bdim), dim3(Hdim), 0, stream>>>(x, W1, b1, W2, b2, out);
}

// Round 5
// 199.570 us; speedup vs baseline: 2.1259x; 1.2922x over previous
//
#include <hip/hip_runtime.h>
#include <stdint.h>

#define Bdim 512
#define Tdim 2000
#define Ddim 20
#define Hdim 128
#define Cdim 10
#define TB 128
#define TBP (TB + 4)     // pad: steady-state prefetch reaches row 129
#define NTILES 16        // 15*128 + 80
#define BETA 0.95f
#define THR 0.8f

typedef float f32x2 __attribute__((ext_vector_type(2)));
typedef float f32x4 __attribute__((ext_vector_type(4)));

#define LO2(q) __builtin_shufflevector(q, q, 0, 1)
#define HI2(q) __builtin_shufflevector(q, q, 2, 3)

// packed fp32 math (the 157-TF path; plain v_fma_f32 is half rate)
#define PK_MUL(d, a, w_) asm volatile("v_pk_mul_f32 %0, %1, %2"     : "=v"(d) : "v"(a), "v"(w_))
#define PK_FMA(d, a, w_) asm volatile("v_pk_fma_f32 %0, %1, %2, %0" : "+v"(d) : "v"(a), "v"(w_))
#define PK_ADD(d, a, b_) asm volatile("v_pk_add_f32 %0, %1, %2"     : "=v"(d) : "v"(a), "v"(b_))

__global__ __launch_bounds__(64, 1) void snn_fused_kernel(
    const float* __restrict__ x,   // [B,T,D]
    const float* __restrict__ W1,  // [H,D]
    const float* __restrict__ b1,  // [H]
    const float* __restrict__ W2,  // [C,H]
    const float* __restrict__ b2,  // [C]
    float* __restrict__ out)       // [B,C]
{
    const int b    = blockIdx.x;
    const int lane = threadIdx.x;  // 0..63

    __shared__ __align__(16) float xs[2][TBP * Ddim];   // 2 x 10560 B
    __shared__ float cnt_s[Hdim];

    // W1 rows for head0 = lane, head1 = lane+64, packed as pairs (rows are 80 B, 8-B aligned)
    f32x2 wA[10], wB[10];
    {
        const f32x2* rA = (const f32x2*)(W1 + lane * Ddim);
        const f32x2* rB = (const f32x2*)(W1 + (lane + 64) * Ddim);
#pragma unroll
        for (int p = 0; p < 10; ++p) { wA[p] = rA[p]; wB[p] = rB[p]; }
    }
    const float biasA  = b1[lane];
    const float biasB  = b1[lane + 64];
    const float biasAm = biasA - THR;
    const float biasBm = biasB - THR;

    const float* xb = x + (size_t)b * Tdim * Ddim;
    const float* const clampMax = x + (size_t)Bdim * Tdim * Ddim - 4;  // last valid 16B chunk

    // stage one 10240 B x-tile via async global->LDS DMA (vmcnt-counted; lgkm untouched)
#define STAGE_TILE(TIDX, BUF) do {                                                     \
        const float* s0_ = xb + (size_t)(TIDX) * TB * Ddim + lane * 4;                 \
        _Pragma("unroll")                                                              \
        for (int k = 0; k < 10; ++k) {                                                 \
            const float* gp_ = s0_ + k * 256;                                          \
            if (gp_ > clampMax) gp_ = clampMax;  /* last block over-stage guard */     \
            __builtin_amdgcn_global_load_lds(                                          \
                (const __attribute__((address_space(1))) unsigned int*)gp_,            \
                (__attribute__((address_space(3))) unsigned int*)&xs[BUF][k * 256],    \
                16, 0, 0);                                                             \
        }                                                                              \
    } while (0)

    STAGE_TILE(0, 0);
    asm volatile("s_waitcnt vmcnt(0)" ::: "memory");

    float    mem0 = 0.f, mem1 = 0.f;
    unsigned cnt0 = 0u,  cnt1 = 0u;
    float    addB0 = biasA, addB1 = biasB;   // bias - THR*spike(prev)

    f32x4 ring[4][5];   // 4 slots x one 80B timestep row; all indices compile-time
    int buf = 0;

    for (int tile = 0; tile < NTILES; ++tile) {
        const int nt = (tile == NTILES - 1) ? (Tdim - TB * (NTILES - 1)) : TB;  // 80 or 128

        if (tile + 1 < NTILES) STAGE_TILE(tile + 1, buf ^ 1);   // overlaps whole tile

        const uint32_t abase = (uint32_t)(uintptr_t)&xs[buf][0];

#define RING_ROW(SLOT, ADDR, ROFF)                                                                              \
        asm volatile("ds_read_b128 %0, %1 offset:%c2" : "=v"(ring[SLOT][0]) : "v"(ADDR), "n"((ROFF) +  0));     \
        asm volatile("ds_read_b128 %0, %1 offset:%c2" : "=v"(ring[SLOT][1]) : "v"(ADDR), "n"((ROFF) + 16));     \
        asm volatile("ds_read_b128 %0, %1 offset:%c2" : "=v"(ring[SLOT][2]) : "v"(ADDR), "n"((ROFF) + 32));     \
        asm volatile("ds_read_b128 %0, %1 offset:%c2" : "=v"(ring[SLOT][3]) : "v"(ADDR), "n"((ROFF) + 48));     \
        asm volatile("ds_read_b128 %0, %1 offset:%c2" : "=v"(ring[SLOT][4]) : "v"(ADDR), "n"((ROFF) + 64));

        // prologue: rows 0,1 -> slots 0,1 (10 outstanding; peak in steady state = 15 = HW cap, no overflow)
        RING_ROW(0, abase, 0)
        RING_ROW(1, abase, 80)

        // steady state: issue row t+2, wait lgkmcnt(10) (=> row t's 5 reads done, DS retires
        // in order), compute row t for both heads with packed-fp32 chains (4-way interleave).
#define SNN_STEP(K) {                                                                               \
        RING_ROW(((K)+2)&3, gaddr, ((K)+2)*80)                                                      \
        asm volatile("s_waitcnt lgkmcnt(10)" ::: "memory");                                         \
        __builtin_amdgcn_sched_barrier(0);                                                          \
        const f32x4 q0q = ring[(K)&3][0], q1q = ring[(K)&3][1], q2q = ring[(K)&3][2],               \
                    q3q = ring[(K)&3][3], q4q = ring[(K)&3][4];                                     \
        const f32x2 p0 = LO2(q0q), p1 = HI2(q0q), p2 = LO2(q1q), p3 = HI2(q1q),                     \
                    p4 = LO2(q2q), p5 = HI2(q2q), p6 = LO2(q3q), p7 = HI2(q3q),                     \
                    p8 = LO2(q4q), p9 = HI2(q4q);                                                   \
        f32x2 ax, ay, bx, by;                                                                       \
        PK_MUL(ax, p0, wA[0]); PK_MUL(ay, p1, wA[1]); PK_MUL(bx, p0, wB[0]); PK_MUL(by, p1, wB[1]); \
        PK_FMA(ax, p2, wA[2]); PK_FMA(ay, p3, wA[3]); PK_FMA(bx, p2, wB[2]); PK_FMA(by, p3, wB[3]); \
        PK_FMA(ax, p4, wA[4]); PK_FMA(ay, p5, wA[5]); PK_FMA(bx, p4, wB[4]); PK_FMA(by, p5, wB[5]); \
        PK_FMA(ax, p6, wA[6]); PK_FMA(ay, p7, wA[7]); PK_FMA(bx, p6, wB[6]); PK_FMA(by, p7, wB[7]); \
        PK_FMA(ax, p8, wA[8]); PK_FMA(ay, p9, wA[9]); PK_FMA(bx, p8, wB[8]); PK_FMA(by, p9, wB[9]); \
        f32x2 as_, bs_;                                                                             \
        PK_ADD(as_, ax, ay); PK_ADD(bs_, bx, by);                                                   \
        const float dotA = as_.x + as_.y;                                                           \
        const float dotB = bs_.x + bs_.y;                                                           \
        mem0 = fmaf(BETA, mem0, dotA) + addB0;                                                      \
        mem1 = fmaf(BETA, mem1, dotB) + addB1;                                                      \
        const bool sA = mem0 > THR, sB = mem1 > THR;                                                \
        cnt0 += sA ? 1u : 0u;  cnt1 += sB ? 1u : 0u;                                                \
        addB0 = sA ? biasAm : biasA;                                                                \
        addB1 = sB ? biasBm : biasB;                                                                \
    }

        for (int tl = 0; tl < nt; tl += 4) {
            const uint32_t gaddr = abase + (uint32_t)(tl * 80);
            SNN_STEP(0)
            SNN_STEP(1)
            SNN_STEP(2)
            SNN_STEP(3)
        }
#undef SNN_STEP

        asm volatile("s_waitcnt lgkmcnt(0)" ::: "memory");   // drain phantom prefetches
        asm volatile("s_waitcnt vmcnt(0)"  ::: "memory");    // next tile's DMA landed
        buf ^= 1;
    }

    // fused epilogue — single wave, no barriers; plain LDS ops (lgkm fully drained above)
    cnt_s[lane]      = (float)cnt0;
    cnt_s[lane + 64] = (float)cnt1;
    __builtin_amdgcn_sched_barrier(0);
    if (lane < Cdim) {
        float dot = 0.0f;
#pragma unroll
        for (int k = 0; k < Hdim; ++k)
            dot = fmaf(cnt_s[k], W2[lane * Hdim + k], dot);
        const float Tf = (float)Tdim;
        const float scale = 1.0f / Tf + 0.1f / (Tf + 1e-6f);
        out[b * Cdim + lane] = fmaf(dot, scale, 1.1f * b2[lane]);
    }
}

extern "C" void kernel_launch(void* const* d_in, const int* in_sizes, int n_in,
                              void* d_out, int out_size, void* d_ws, size_t ws_size,
                              hipStream_t stream) {
    const float* x  = (const float*)d_in[0];
    const float* W1 = (const float*)d_in[1];
    const float* b1 = (const float*)d_in[2];
    const float* W2 = (const float*)d_in[3];
    const float* b2 = (const float*)d_in[4];
    float* out = (float*)d_out;

    snn_fused_kernel<<<dim3(Bdim), dim3(64), 0, stream>>>(x, W1, b1, W2, b2, out);
}